// Round 12
// baseline (1063.539 us; speedup 1.0000x reference)
//
#include <hip/hip_runtime.h>
#include <stdint.h>

typedef _Float16 f16;
typedef _Float16 f16x2 __attribute__((ext_vector_type(2)));
typedef _Float16 f16x8 __attribute__((ext_vector_type(8)));
typedef float f32x4 __attribute__((ext_vector_type(4)));

#define SEQ   512
#define BATCH 128
#define DIM   512
#define HID   256
#define G4    1024

typedef const __attribute__((address_space(1))) void* gas1p;
typedef __attribute__((address_space(3))) void* las3p;

__device__ __forceinline__ uint32_t pk2(float a, float b){
  return __builtin_bit_cast(uint32_t, __builtin_amdgcn_cvt_pkrtz(a, b));
}

__device__ __forceinline__ int sdot4(uint32_t a, uint32_t b, int c){
#if __has_builtin(__builtin_amdgcn_sdot4)
  return __builtin_amdgcn_sdot4(a, b, c, false);
#else
  int s = c;
  #pragma unroll
  for (int i = 0; i < 4; ++i){
    int ai = (int)(signed char)((a >> (8*i)) & 0xff);
    int bi = (int)(signed char)((b >> (8*i)) & 0xff);
    s += ai*bi;
  }
  return s;
#endif
}

__device__ __forceinline__ int dotq(uint4 w, uint4 h, int acc){
  acc = sdot4(w.x, h.x, acc);
  acc = sdot4(w.y, h.y, acc);
  acc = sdot4(w.z, h.z, acc);
  acc = sdot4(w.w, h.w, acc);
  return acc;
}

__device__ __forceinline__ float sigm(float x){
  return __builtin_amdgcn_rcpf(1.0f + __expf(-x));
}
__device__ __forceinline__ float tanh_(float x){
  return 1.0f - 2.0f*__builtin_amdgcn_rcpf(__expf(2.0f*x) + 1.0f);
}

__device__ __forceinline__ uint32_t q8pack(float4 v){
  int a = __float2int_rn(v.x*2048.f); a = a > 127 ? 127 : (a < -127 ? -127 : a);
  int b = __float2int_rn(v.y*2048.f); b = b > 127 ? 127 : (b < -127 ? -127 : b);
  int c = __float2int_rn(v.z*2048.f); c = c > 127 ? 127 : (c < -127 ? -127 : c);
  int d = __float2int_rn(v.w*2048.f); d = d > 127 ? 127 : (d < -127 ? -127 : d);
  return (uint32_t)(a & 0xff) | ((uint32_t)(b & 0xff) << 8) |
         ((uint32_t)(c & 0xff) << 16) | ((uint32_t)(d & 0xff) << 24);
}

// ---------------- phase 0: fp32 -> f16 convert (vectorized, 8 elems/thread) ----
__global__ void __launch_bounds__(256) cvt_f16_kernel(const float* __restrict__ in,
                                                      f16* __restrict__ out, int n8){
  int i = blockIdx.x*blockDim.x + threadIdx.x;
  if (i >= n8) return;
  const float4* p = (const float4*)in;
  float4 a = p[2*i], b = p[2*i+1];
  uint4 r;
  r.x = pk2(a.x, a.y); r.y = pk2(a.z, a.w);
  r.z = pk2(b.x, b.y); r.w = pk2(b.z, b.w);
  ((uint4*)out)[i] = r;
}

// ---------------- phase 0b: quantize W_hh into THREE stream layouts ------------
// Row r (0..1023) has 16 quads (quad Q = k 16Q..16Q+15).
// WL [6][1024]: quads {0,1,2,8,9,10}  -> staged to LDS        (96 KB)
// WG [6][1024]: quads {3,4,5,11,12,13}-> streamed from L2     (96 KB)
// WR [512][8] : quads {6,7,14,15} for thread t's rows r0,r1   (64 KB, registers)
//   thread t: wave=t>>6, lane=t&63, j=wave*32+(lane&31), p=lane>>5
//   r0 = j + p*256, r1 = r0 + 512;  WR[t*8+s]: s<4 -> r0, else r1; quad {6,7,14,15}[s&3]
__global__ void __launch_bounds__(256) prep_whh8(const float* __restrict__ Whh,
                                                 uint4* __restrict__ WL,
                                                 uint4* __restrict__ WG,
                                                 uint4* __restrict__ WR){
  int tid = blockIdx.x*256 + threadIdx.x;      // 0..16383
  int r, Q; uint4* dst; int idx;
  if (tid < 6144){
    const int QLt[6] = {0,1,2,8,9,10};
    int q = tid >> 10; r = tid & 1023;
    Q = QLt[q]; dst = WL; idx = tid;
  } else if (tid < 12288){
    const int QGt[6] = {3,4,5,11,12,13};
    int i = tid - 6144;
    int q = i >> 10; r = i & 1023;
    Q = QGt[q]; dst = WG; idx = i;
  } else {
    const int QRt[4] = {6,7,14,15};
    int i = tid - 12288;
    int t = i >> 3, s = i & 7;
    int lane = t & 63, wave = t >> 6;
    int j = wave*32 + (lane & 31), p = lane >> 5;
    r = (s < 4) ? (j + p*256) : (j + p*256 + 512);
    Q = QRt[s & 3]; dst = WR; idx = i;
  }
  const float* src = Whh + r*HID + Q*16;
  float4 v0 = *(const float4*)(src);
  float4 v1 = *(const float4*)(src + 4);
  float4 v2 = *(const float4*)(src + 8);
  float4 v3 = *(const float4*)(src + 12);
  dst[idx] = make_uint4(q8pack(v0), q8pack(v1), q8pack(v2), q8pack(v3));
}

// ---------------- phase 1: xg = x . W_ih^T + bias, f16 MFMA --------------------
// Epilogue writes QUAD layout: for gate col g, unit u=g&255, type tau=g>>8:
// C[m*1024 + u*4 + tau]  (so each unit's {i,f,g,o} are contiguous f16x4).
#define BM 128
#define BN 128
#define BK 64

__global__ void __launch_bounds__(256) gemm_xg_kernel(const f16* __restrict__ A,
                                                      const f16* __restrict__ Bm,
                                                      const float* __restrict__ bih,
                                                      const float* __restrict__ bhh,
                                                      f16* __restrict__ C){
  __shared__ __align__(16) f16 ldsA[BM*BK];
  __shared__ __align__(16) f16 ldsB[BN*BK];
  const int tid  = threadIdx.x;
  const int wave = tid >> 6;
  const int lane = tid & 63;
  const int bid  = blockIdx.x;
  const int nt   = bid & 7;
  const int mt   = bid >> 3;
  const long m0  = (long)mt * BM;
  const int n0   = nt * BN;
  const int wm   = wave >> 1, wn = wave & 1;
  const int lrow = lane >> 3;
  const int lk   = (lane & 7) * 8;

  f32x4 acc[4][4];
  #pragma unroll
  for (int i=0;i<4;++i)
    #pragma unroll
    for (int j=0;j<4;++j) acc[i][j] = (f32x4){0.f,0.f,0.f,0.f};

  auto ldsAq = (__attribute__((address_space(3))) char*)ldsA;
  auto ldsBq = (__attribute__((address_space(3))) char*)ldsB;

  for (int kt = 0; kt < DIM/BK; ++kt){
    const int k0 = kt*BK;
    __syncthreads();
    #pragma unroll
    for (int i = 0; i < 4; ++i){
      const int seg = wave*4 + i;
      const f16* ga = A  + (m0 + seg*8 + lrow)*DIM + (k0 + lk);
      const f16* gb = Bm + (long)(n0 + seg*8 + lrow)*DIM + (k0 + lk);
      __builtin_amdgcn_global_load_lds((gas1p)ga, (las3p)(ldsAq + seg*1024), 16, 0, 0);
      __builtin_amdgcn_global_load_lds((gas1p)gb, (las3p)(ldsBq + seg*1024), 16, 0, 0);
    }
    __syncthreads();
    #pragma unroll
    for (int kk = 0; kk < 2; ++kk){
      f16x8 af[4], bf[4];
      const int kb = kk*32 + (lane>>4)*8;
      #pragma unroll
      for (int mi=0; mi<4; ++mi){
        af[mi] = *(const f16x8*)(ldsA + (wm*64 + mi*16 + (lane&15))*BK + kb);
        bf[mi] = *(const f16x8*)(ldsB + (wn*64 + mi*16 + (lane&15))*BK + kb);
      }
      #pragma unroll
      for (int mi=0;mi<4;++mi)
        #pragma unroll
        for (int ni=0;ni<4;++ni)
          acc[mi][ni] = __builtin_amdgcn_mfma_f32_16x16x32_f16(af[mi], bf[ni], acc[mi][ni], 0,0,0);
    }
  }
  float bias[4];
  #pragma unroll
  for (int ni=0;ni<4;++ni){
    int col = n0 + wn*64 + ni*16 + (lane&15);
    bias[ni] = bih[col] + bhh[col];
  }
  #pragma unroll
  for (int mi=0;mi<4;++mi){
    #pragma unroll
    for (int ni=0;ni<4;++ni){
      int col = n0 + wn*64 + ni*16 + (lane&15);
      int cpos = (col & 255)*4 + (col >> 8);       // quad layout
      #pragma unroll
      for (int r=0;r<4;++r){
        long row = m0 + wm*64 + mi*16 + (lane>>4)*4 + r;
        C[row*G4 + cpos] = (f16)(acc[mi][ni][r] + bias[ni]);
      }
    }
  }
}

// ---------------- phase 2: sequential LSTM (i8 dot4), 3-stream weights ---------
// 128 blocks x 512 threads (8 waves, 2/SIMD). Lanes l and l^32 share unit
// j = wave*32 + (lane&31); p = lane>>5. p=0 computes gate rows i (j), g (j+512);
// p=1 computes f (j+256), o (j+768). IG exchanged via shfl_xor(32); ONE barrier.
// Weights per row (64 words): quads {0,1,2,8,9,10} from a 96KB LDS slab,
// {3,4,5,11,12,13} streamed from L2 (shared by all blocks -> L2-resident),
// {6,7,14,15} in a SMALL register array (32 words/thread -> RA keeps it).
// Anti-LICM opaque asm each iteration stops the compiler from hoisting the
// stream loads (which would recreate the 472us spill disaster of r5-r11).
__global__ void
__attribute__((amdgpu_flat_work_group_size(512, 512)))
lstm8_kernel(const f16* __restrict__ xq,
             const uint4* __restrict__ WLg,
             const uint4* __restrict__ WG,
             const uint4* __restrict__ WR,
             const float* __restrict__ fcw,
             const float* __restrict__ fcb,
             float* __restrict__ out){
  extern __shared__ __align__(16) char smem[];
  uint4*   WL  = (uint4*)smem;                 // 6144 uint4 = 96 KiB
  uint8_t* h8  = (uint8_t*)(smem + 98304);     // [2][256] i8 h double buffer
  float*   red = (float*)(smem + 98816);       // 256 f32 reduce
  const int t = threadIdx.x;
  const int b = blockIdx.x;
  const int lane = t & 63, wave = t >> 6;
  const int j = wave*32 + (lane & 31);
  const int p = lane >> 5;
  const float invS = 1.0f / (2048.0f * 127.0f);

  // stage LDS slab (coalesced, one-time)
  #pragma unroll
  for (int i = 0; i < 12; ++i) WL[i*512 + t] = WLg[i*512 + t];

  // small register weight array: quads {6,7,14,15} x rows {r0,r1} = 8 uint4
  uint4 wr[8];
  {
    const uint4* wp = WR + (size_t)t*8;
    #pragma unroll
    for (int i = 0; i < 8; ++i) wr[i] = wp[i];
  }

  if (t < 128) ((uint32_t*)h8)[t] = 0;         // zero both h buffers

  const f16* xrow = xq + (long)b * SEQ * G4;
  ushort4 xv = *(const ushort4*)(xrow + j*4);  // unit quad {i,f,g,o}
  float c = 0.f, hlast = 0.f;
  const int r0 = j + p*256;                    // p=0: i-row, p=1: f-row
  const int r1 = r0 + 512;                     // p=0: g-row, p=1: o-row
  uintptr_t wga = (uintptr_t)WG;
  __syncthreads();

  for (int ts = 0; ts < SEQ; ++ts){
    ushort4 xc = xv;
    if (ts + 1 < SEQ) xv = *(const ushort4*)(xrow + (ts+1)*G4 + j*4);

    uint32_t wlo = 0;
    asm("" : "+v"(wlo));                       // opaque: defeats LICM on WL
    asm("" : "+v"(wga));                       // opaque: defeats LICM on WG
    const uint4* wgp = (const uint4*)wga;
    const uint4* hq = (const uint4*)&h8[(ts & 1)*256];

    int a0 = 0, a1 = 0;
    {                                          // ---- chunk A: k 0..127
      uint4 hv[8];
      #pragma unroll
      for (int q = 0; q < 8; ++q) hv[q] = hq[q];
      #pragma unroll
      for (int q = 0; q < 3; ++q){             // LDS quads 0,1,2
        uint4 w0 = WL[wlo + q*1024 + r0];
        uint4 w1 = WL[wlo + q*1024 + r1];
        a0 = dotq(w0, hv[q], a0);
        a1 = dotq(w1, hv[q], a1);
      }
      #pragma unroll
      for (int q = 0; q < 3; ++q){             // L2 quads 3,4,5
        uint4 w0 = wgp[q*1024 + r0];
        uint4 w1 = wgp[q*1024 + r1];
        a0 = dotq(w0, hv[3+q], a0);
        a1 = dotq(w1, hv[3+q], a1);
      }
      a0 = dotq(wr[0], hv[6], a0);             // reg quads 6,7
      a0 = dotq(wr[1], hv[7], a0);
      a1 = dotq(wr[4], hv[6], a1);
      a1 = dotq(wr[5], hv[7], a1);
    }
    {                                          // ---- chunk B: k 128..255
      uint4 hv[8];
      #pragma unroll
      for (int q = 0; q < 8; ++q) hv[q] = hq[8 + q];
      #pragma unroll
      for (int q = 0; q < 3; ++q){             // LDS quads 8,9,10
        uint4 w0 = WL[wlo + (3+q)*1024 + r0];
        uint4 w1 = WL[wlo + (3+q)*1024 + r1];
        a0 = dotq(w0, hv[q], a0);
        a1 = dotq(w1, hv[q], a1);
      }
      #pragma unroll
      for (int q = 0; q < 3; ++q){             // L2 quads 11,12,13
        uint4 w0 = wgp[(3+q)*1024 + r0];
        uint4 w1 = wgp[(3+q)*1024 + r1];
        a0 = dotq(w0, hv[3+q], a0);
        a1 = dotq(w1, hv[3+q], a1);
      }
      a0 = dotq(wr[2], hv[6], a0);             // reg quads 14,15
      a0 = dotq(wr[3], hv[7], a0);
      a1 = dotq(wr[6], hv[6], a1);
      a1 = dotq(wr[7], hv[7], a1);
    }

    // p=0: a0 -> gate i, a1 -> gate g.  p=1: a0 -> f, a1 -> o.
    ushort xlo = p ? xc.y : xc.x;
    ushort xhi = p ? xc.w : xc.z;
    float gA = (float)__builtin_bit_cast(f16, xlo) + (float)a0*invS;
    float gB = (float)__builtin_bit_cast(f16, xhi) + (float)a1*invS;
    float IG  = sigm(gA) * tanh_(gB);          // meaningful on p=0 lanes
    float IGx = __shfl_xor(IG, 32);            // p=1 receives i*g of its unit
    if (p){
      c     = sigm(gA)*c + IGx;                // f*c + i*g
      hlast = sigm(gB) * tanh_(c);             // o * tanh(c)
      h8[((ts+1) & 1)*256 + j] = (uint8_t)(__float2int_rn(hlast*127.f) & 0xff);
    }
    __syncthreads();                           // ONE barrier per step
  }

  // ---- fused FC head (hlast valid on p=1 lanes, one per unit)
  if (p) red[j] = hlast * fcw[j];
  __syncthreads();
  if (t < 64){
    float s = red[t] + red[t+64] + red[t+128] + red[t+192];
    #pragma unroll
    for (int off = 32; off; off >>= 1) s += __shfl_down(s, off);
    if (t == 0) out[b] = s + fcb[0];
  }
}

extern "C" void kernel_launch(void* const* d_in, const int* in_sizes, int n_in,
                              void* d_out, int out_size, void* d_ws, size_t ws_size,
                              hipStream_t stream) {
  const float* x   = (const float*)d_in[0];
  const float* Wih = (const float*)d_in[1];
  const float* Whh = (const float*)d_in[2];
  const float* bih = (const float*)d_in[3];
  const float* bhh = (const float*)d_in[4];
  const float* fcw = (const float*)d_in[5];
  const float* fcb = (const float*)d_in[6];
  float* out = (float*)d_out;

  char* ws = (char*)d_ws;
  f16*   xh  = (f16*)ws;                                   //  67,108,864 B
  f16*   Wh  = (f16*)(ws + 67108864);                      //   1,048,576 B
  f16*   xq  = (f16*)(ws + 68157440);                      // 134,217,728 B
  uint4* WL  = (uint4*)(ws + 202375168);                   //      98,304 B
  uint4* WG  = (uint4*)(ws + 202473472);                   //      98,304 B
  uint4* WR  = (uint4*)(ws + 202571776);                   //      65,536 B

  cvt_f16_kernel<<<16384, 256, 0, stream>>>(x,   xh, 33554432/8);
  cvt_f16_kernel<<<256,   256, 0, stream>>>(Wih, Wh, 524288/8);
  prep_whh8<<<64, 256, 0, stream>>>(Whh, WL, WG, WR);
  gemm_xg_kernel<<<4096, 256, 0, stream>>>(xh, Wh, bih, bhh, xq);
  (void)hipFuncSetAttribute(reinterpret_cast<const void*>(lstm8_kernel),
                            hipFuncAttributeMaxDynamicSharedMemorySize, 99840);
  lstm8_kernel<<<BATCH, 512, 99840, stream>>>(xq, WL, WG, WR, fcw, fcb, out);
}